// Round 4
// baseline (503.496 us; speedup 1.0000x reference)
//
#include <hip/hip_runtime.h>
#include <hip/hip_bf16.h>

// GptOssMoEExperts on MI355X — round 3 resubmit (round 3 never ran: broker timeout).
// Router is a no-op (sum of softmax over top-k == 1):
//   out = (gate * silu(up)) @ down_w^T + down_b,  [gate|up] = hs @ gate_up_w^T + b.
//
// Changes vs round 2:
//  - convert3 kernel DELETED: fp32->bf16 conversion fused into GEMM staging
//    (global fp32 -> regs -> cvt -> swizzled ds_write). Saves a full 220 MB
//    round-trip (~35 us).
//  - Single barrier + lgkmcnt(0) per K-tile (was 4 barriers): reg-staged
//    double-buffer, loads for tile t+2 issued in phase t, written in t+1.
//    Compiler's in-order vmcnt tracking provides the counted wait (vmcnt(8))
//    at the ds_write use point automatically; sched_barrier(0) fences keep
//    loads in their issue phase.
//  - LDS: 2 x 32 KiB slots per kernel; same verified XOR swizzle (0 conflicts
//    in round 2), same MFMA fragment/epilogue mappings (passed absmax 2.9e-3).

typedef __bf16 bf16_t;
typedef bf16_t bf16x8 __attribute__((ext_vector_type(8)));
typedef float f32x4 __attribute__((ext_vector_type(4)));

#define SEQ   4096
#define HID   2880
#define INTER 2880
#define BK    32
#define NT    90   // 2880 / 32, same K for both GEMMs

#define BARRIER()                                                             \
  do {                                                                        \
    __builtin_amdgcn_sched_barrier(0);                                        \
    __builtin_amdgcn_s_barrier();                                             \
    __builtin_amdgcn_sched_barrier(0);                                        \
  } while (0)

#define LGKM0() asm volatile("s_waitcnt lgkmcnt(0)" ::: "memory")

// Byte offset inside a [rows][32 bf16] LDS tile, row-pair XOR swizzle.
// slot = ((row&1)<<2 | chunk) ^ ((row>>1)&7); byte = (row>>1)*128 + slot*16.
// 16-lane column-slice reads and 64-lane staging writes are both uniform
// across banks (0 conflicts measured in round 2).
__device__ __forceinline__ int swz(int row, int chunk) {
  int slot = (((row & 1) << 2) | chunk) ^ ((row >> 1) & 7);
  return ((row >> 1) << 7) + (slot << 4);
}

__device__ __forceinline__ bf16x8 cvt8(f32x4 x, f32x4 y) {
  bf16x8 r;
  r[0] = (bf16_t)x[0]; r[1] = (bf16_t)x[1]; r[2] = (bf16_t)x[2]; r[3] = (bf16_t)x[3];
  r[4] = (bf16_t)y[0]; r[5] = (bf16_t)y[1]; r[6] = (bf16_t)y[2]; r[7] = (bf16_t)y[3];
  return r;
}

// ---------------------------------------------------------------------------
// K1: fused gate/up GEMM + silu.  BM=256, BN=96 (per mat), 8 waves
// (4M x 2N), per-wave 64x48 per mat, 16x16x32 MFMA.  LDS slot = A 16K + G 8K
// + U 8K = 32K, double-buffered = 64 KiB.  Per thread per K-tile: 8 fp32x4
// global loads (A row pair 2 chunks, G 1, U 1), 4 ds_write_b128 after cvt.
// ---------------------------------------------------------------------------

#define G1_DECL(S) f32x4 S##a0, S##a1, S##a2, S##a3, S##g0, S##g1, S##u0, S##u1

#define G1_ISSUE(S, KT)                                                       \
  do {                                                                        \
    const int kk_ = ((KT) < NT ? (KT) : (NT - 1)) * BK;                       \
    S##a0 = *(const f32x4*)(pA0 + kk_);                                       \
    S##a1 = *(const f32x4*)(pA0 + kk_ + 4);                                   \
    S##a2 = *(const f32x4*)(pA1 + kk_);                                       \
    S##a3 = *(const f32x4*)(pA1 + kk_ + 4);                                   \
    S##g0 = *(const f32x4*)(pG + kk_);                                        \
    S##g1 = *(const f32x4*)(pG + kk_ + 4);                                    \
    S##u0 = *(const f32x4*)(pU + kk_);                                        \
    S##u1 = *(const f32x4*)(pU + kk_ + 4);                                    \
  } while (0)

#define G1_WRITE(S, wp)                                                       \
  do {                                                                        \
    *(bf16x8*)((wp) + wA0) = cvt8(S##a0, S##a1);                              \
    *(bf16x8*)((wp) + wA1) = cvt8(S##a2, S##a3);                              \
    *(bf16x8*)((wp) + wG)  = cvt8(S##g0, S##g1);                              \
    *(bf16x8*)((wp) + wU)  = cvt8(S##u0, S##u1);                              \
  } while (0)

// One K-tile: issue loads for T+2 into Si; read+MFMA tile T from rp;
// cvt+write tile T+1 from Sw into wp; drain LDS; barrier.
#define G1_PHASE(T, Si, Sw, rp, wp)                                           \
  do {                                                                        \
    G1_ISSUE(Si, (T) + 2);                                                    \
    bf16x8 af[4], gf[3], uf[3];                                               \
    _Pragma("unroll") for (int m = 0; m < 4; ++m)                             \
      af[m] = *(const bf16x8*)((rp) + rdA[m]);                                \
    _Pragma("unroll") for (int n = 0; n < 3; ++n) {                           \
      gf[n] = *(const bf16x8*)((rp) + rdG[n]);                                \
      uf[n] = *(const bf16x8*)((rp) + rdU[n]);                                \
    }                                                                         \
    __builtin_amdgcn_s_setprio(1);                                            \
    _Pragma("unroll") for (int m = 0; m < 4; ++m)                             \
      _Pragma("unroll") for (int n = 0; n < 3; ++n) {                         \
        accg[m][n] = __builtin_amdgcn_mfma_f32_16x16x32_bf16(af[m], gf[n], accg[m][n], 0, 0, 0); \
        accu[m][n] = __builtin_amdgcn_mfma_f32_16x16x32_bf16(af[m], uf[n], accu[m][n], 0, 0, 0); \
      }                                                                       \
    __builtin_amdgcn_s_setprio(0);                                            \
    if ((T) + 1 < NT) { G1_WRITE(Sw, wp); }                                   \
    LGKM0();                                                                  \
    BARRIER();                                                                \
  } while (0)

__global__ __launch_bounds__(512) void gemm1(const float* __restrict__ A,
                                             const float* __restrict__ GW,
                                             const float* __restrict__ bias,
                                             bf16_t* __restrict__ X) {
  __shared__ char sm[2 * 32768];
  char* const sm0 = sm;
  char* const sm1 = sm + 32768;

  const int tid = threadIdx.x;
  const int w = tid >> 6, l = tid & 63;
  const int wm = w >> 1, wn = w & 1;          // 4M x 2N wave grid
  const int l15 = l & 15, l4 = l >> 4;
  const int row0 = blockIdx.x * 256;
  const int col0 = blockIdx.y * 96;

  // Staging source pointers (fp32).  Thread covers: A rows srow & srow+128
  // (chunk tid&3), G row srow (clamped to 95), U row srow (clamped).
  const int srow = tid >> 2;                  // 0..127
  const int sch8 = (tid & 3) * 8;
  const float* const pA0 = A + (size_t)(row0 + srow) * HID + sch8;
  const float* const pA1 = pA0 + (size_t)128 * HID;
  const int grow = srow < 96 ? srow : 95;     // rows 96..127 are dead slots
  const float* const pG = GW + (size_t)(col0 + grow) * HID + sch8;
  const float* const pU = GW + (size_t)(INTER + col0 + grow) * HID + sch8;

  // LDS write offsets (A at 0, G at 16384, U at 24576).
  const int wA0 = swz(srow, tid & 3);
  const int wA1 = swz(128 + srow, tid & 3);
  const int wG  = 16384 + swz(srow, tid & 3);
  const int wU  = 24576 + swz(srow, tid & 3);

  // LDS read offsets (loop-invariant).
  int rdA[4], rdG[3], rdU[3];
#pragma unroll
  for (int m = 0; m < 4; ++m) rdA[m] = swz(wm * 64 + m * 16 + l15, l4);
#pragma unroll
  for (int n = 0; n < 3; ++n) {
    rdG[n] = 16384 + swz(wn * 48 + n * 16 + l15, l4);
    rdU[n] = 24576 + swz(wn * 48 + n * 16 + l15, l4);
  }

  f32x4 accg[4][3], accu[4][3];
#pragma unroll
  for (int m = 0; m < 4; ++m)
#pragma unroll
    for (int n = 0; n < 3; ++n) {
      accg[m][n] = (f32x4){0.f, 0.f, 0.f, 0.f};
      accu[m][n] = (f32x4){0.f, 0.f, 0.f, 0.f};
    }

  G1_DECL(s0_);
  G1_DECL(s1_);

  // Prologue: L(0)->s0, L(1)->s1, W(0)->slot0.
  G1_ISSUE(s0_, 0);
  G1_ISSUE(s1_, 1);
  G1_WRITE(s0_, sm0);
  LGKM0();
  BARRIER();

#pragma unroll 1
  for (int t = 0; t < NT; t += 2) {
    G1_PHASE(t,     s0_, s1_, sm0, sm1);  // compute t (slot0), write t+1
    G1_PHASE(t + 1, s1_, s0_, sm1, sm0);  // compute t+1 (slot1), write t+2
  }

  // Epilogue: x = (gate+bg) * silu(up+bu).  C/D: col=lane&15, row=(lane>>4)*4+j.
#pragma unroll
  for (int n = 0; n < 3; ++n) {
    const int col = col0 + wn * 48 + n * 16 + l15;
    const float bg = bias[col];
    const float bu = bias[INTER + col];
#pragma unroll
    for (int m = 0; m < 4; ++m) {
      const int r = row0 + wm * 64 + m * 16 + l4 * 4;
#pragma unroll
      for (int j = 0; j < 4; ++j) {
        const float g = accg[m][n][j] + bg;
        const float u = accu[m][n][j] + bu;
        X[(size_t)(r + j) * INTER + col] = (bf16_t)(g * (u / (1.f + __expf(-u))));
      }
    }
  }
}

// ---------------------------------------------------------------------------
// K2: out = x @ down_w^T + down_b.  BM=256, BN=192, 8 waves (4M x 2N),
// per-wave 64x96, 16x16x32 MFMA.  A (x) is bf16: staged directly; B (down_w)
// is fp32: cvt-fused.  LDS slot = A 16K + B 16K = 32K, double-buffered.
// Per thread per K-tile: 2 bf16x8 + 4 f32x4 loads, 4 ds_write_b128.
// ---------------------------------------------------------------------------

#define G2_DECL(S) bf16x8 S##v0, S##v1; f32x4 S##b0, S##b1, S##b2, S##b3

#define G2_ISSUE(S, KT)                                                       \
  do {                                                                        \
    const int kk_ = ((KT) < NT ? (KT) : (NT - 1)) * BK;                       \
    S##v0 = *(const bf16x8*)(pA0 + kk_);                                      \
    S##v1 = *(const bf16x8*)(pA1 + kk_);                                      \
    S##b0 = *(const f32x4*)(pB0 + kk_);                                       \
    S##b1 = *(const f32x4*)(pB0 + kk_ + 4);                                   \
    S##b2 = *(const f32x4*)(pB1 + kk_);                                       \
    S##b3 = *(const f32x4*)(pB1 + kk_ + 4);                                   \
  } while (0)

#define G2_WRITE(S, wp)                                                       \
  do {                                                                        \
    *(bf16x8*)((wp) + wA0) = S##v0;                                           \
    *(bf16x8*)((wp) + wA1) = S##v1;                                           \
    *(bf16x8*)((wp) + wB0) = cvt8(S##b0, S##b1);                              \
    *(bf16x8*)((wp) + wB1) = cvt8(S##b2, S##b3);                              \
  } while (0)

#define G2_PHASE(T, Si, Sw, rp, wp)                                           \
  do {                                                                        \
    G2_ISSUE(Si, (T) + 2);                                                    \
    bf16x8 af[4], bf[6];                                                      \
    _Pragma("unroll") for (int m = 0; m < 4; ++m)                             \
      af[m] = *(const bf16x8*)((rp) + rdA[m]);                                \
    _Pragma("unroll") for (int n = 0; n < 6; ++n)                             \
      bf[n] = *(const bf16x8*)((rp) + rdB[n]);                                \
    __builtin_amdgcn_s_setprio(1);                                            \
    _Pragma("unroll") for (int m = 0; m < 4; ++m)                             \
      _Pragma("unroll") for (int n = 0; n < 6; ++n)                           \
        acc[m][n] = __builtin_amdgcn_mfma_f32_16x16x32_bf16(af[m], bf[n], acc[m][n], 0, 0, 0); \
    __builtin_amdgcn_s_setprio(0);                                            \
    if ((T) + 1 < NT) { G2_WRITE(Sw, wp); }                                   \
    LGKM0();                                                                  \
    BARRIER();                                                                \
  } while (0)

__global__ __launch_bounds__(512) void gemm2(const bf16_t* __restrict__ A,
                                             const float* __restrict__ BW,
                                             const float* __restrict__ bias,
                                             float* __restrict__ out) {
  __shared__ char sm[2 * 32768];
  char* const sm0 = sm;
  char* const sm1 = sm + 32768;

  const int tid = threadIdx.x;
  const int w = tid >> 6, l = tid & 63;
  const int wm = w >> 1, wn = w & 1;
  const int l15 = l & 15, l4 = l >> 4;
  const int row0 = blockIdx.x * 256;
  const int col0 = blockIdx.y * 192;

  const int srow = tid >> 2;
  const int sch8 = (tid & 3) * 8;
  const bf16_t* const pA0 = A + (size_t)(row0 + srow) * INTER + sch8;
  const bf16_t* const pA1 = pA0 + (size_t)128 * INTER;
  const int br = (128 + srow) < 192 ? (128 + srow) : 191;  // rows >=192 dead
  const float* const pB0 = BW + (size_t)(col0 + srow) * INTER + sch8;
  const float* const pB1 = BW + (size_t)(col0 + br) * INTER + sch8;

  const int wA0 = swz(srow, tid & 3);
  const int wA1 = swz(128 + srow, tid & 3);
  const int wB0 = 16384 + swz(srow, tid & 3);
  const int wB1 = 16384 + swz(128 + srow, tid & 3);

  int rdA[4], rdB[6];
#pragma unroll
  for (int m = 0; m < 4; ++m) rdA[m] = swz(wm * 64 + m * 16 + l15, l4);
#pragma unroll
  for (int n = 0; n < 6; ++n) rdB[n] = 16384 + swz(wn * 96 + n * 16 + l15, l4);

  f32x4 acc[4][6];
#pragma unroll
  for (int m = 0; m < 4; ++m)
#pragma unroll
    for (int n = 0; n < 6; ++n) acc[m][n] = (f32x4){0.f, 0.f, 0.f, 0.f};

  G2_DECL(s0_);
  G2_DECL(s1_);

  G2_ISSUE(s0_, 0);
  G2_ISSUE(s1_, 1);
  G2_WRITE(s0_, sm0);
  LGKM0();
  BARRIER();

#pragma unroll 1
  for (int t = 0; t < NT; t += 2) {
    G2_PHASE(t,     s0_, s1_, sm0, sm1);
    G2_PHASE(t + 1, s1_, s0_, sm1, sm0);
  }

#pragma unroll
  for (int n = 0; n < 6; ++n) {
    const int col = col0 + wn * 96 + n * 16 + l15;
    const float bb = bias[col];
#pragma unroll
    for (int m = 0; m < 4; ++m) {
      const int r = row0 + wm * 64 + m * 16 + l4 * 4;
#pragma unroll
      for (int j = 0; j < 4; ++j)
        out[(size_t)(r + j) * HID + col] = acc[m][n][j] + bb;
    }
  }
}

// ---------------------------------------------------------------------------
extern "C" void kernel_launch(void* const* d_in, const int* in_sizes, int n_in,
                              void* d_out, int out_size, void* d_ws, size_t ws_size,
                              hipStream_t stream) {
  (void)in_sizes; (void)n_in; (void)out_size; (void)ws_size;

  const float* hs  = (const float*)d_in[0];  // (4096, 2880)
  // d_in[1] router_w, d_in[2] router_b: unused — sum(softmax(topk)) == 1.
  const float* guw = (const float*)d_in[3];  // (5760, 2880)
  const float* gub = (const float*)d_in[4];  // (5760,)
  const float* dww = (const float*)d_in[5];  // (2880, 2880)
  const float* dwb = (const float*)d_in[6];  // (2880,)
  float* out = (float*)d_out;                // (4096, 2880)

  bf16_t* xb = (bf16_t*)d_ws;                // (4096, 2880) bf16 intermediate

  dim3 g1(SEQ / 256, INTER / 96);            // 16 x 30 = 480 blocks
  gemm1<<<g1, 512, 0, stream>>>(hs, guw, gub, xb);

  dim3 g2(SEQ / 256, HID / 192);             // 16 x 15 = 240 blocks
  gemm2<<<g2, 512, 0, stream>>>(xb, dww, dwb, out);
}

// Round 5
// 367.480 us; speedup vs baseline: 1.3701x; 1.3701x over previous
//
#include <hip/hip_runtime.h>
#include <hip/hip_bf16.h>

// GptOssMoEExperts on MI355X — round 5.
// Router is a no-op (sum of softmax over top-k == 1):
//   out = (gate * silu(up)) @ down_w^T + down_b,  [gate|up] = hs @ gate_up_w^T + b.
//
// Round-4 reg-staged rewrite REGRESSED (273 us, MfmaUtil 20%): exposed
// vmcnt->cvt->ds_write->lgkm0 serial tail per phase. Reverted to the round-2
// structure (convert3 + global_load_lds + ring-4 + counted vmcnt(8), 154 us,
// MfmaUtil 37.6%, 0 bank conflicts) with ONE change: the two phases per
// K-tile are merged into one -> 1 barrier per K-tile instead of 4. The
// compiler's fine-grained lgkmcnt scheduling overlaps the 10 ds_read_b128 and
// 4 stage-issues with the 24 MFMAs inside the single phase window.

typedef __bf16 bf16_t;
typedef bf16_t bf16x8 __attribute__((ext_vector_type(8)));
typedef bf16_t bf16x4 __attribute__((ext_vector_type(4)));
typedef float f32x4 __attribute__((ext_vector_type(4)));

#define SEQ   4096
#define HID   2880
#define INTER 2880
#define BK    32
#define NT    90   // 2880 / 32, same K depth for both GEMMs

#define GLD16(srcp, ldsp)                                                     \
  __builtin_amdgcn_global_load_lds(                                           \
      (const __attribute__((address_space(1))) unsigned int*)(srcp),          \
      (__attribute__((address_space(3))) unsigned int*)(ldsp), 16, 0, 0)

#define BARRIER()                                                             \
  do {                                                                        \
    __builtin_amdgcn_sched_barrier(0);                                        \
    __builtin_amdgcn_s_barrier();                                             \
    __builtin_amdgcn_sched_barrier(0);                                        \
  } while (0)

#define VMCNT(n) asm volatile("s_waitcnt vmcnt(" #n ")" ::: "memory")

// Byte offset inside a [rows][32 bf16] LDS tile, row-pair XOR swizzle.
// slot = ((row&1)<<2 | chunk) ^ ((row>>1)&7); byte = (row>>1)*128 + slot*16.
// Measured 0 bank conflicts (round 2) for both the 16-lane column-slice reads
// and the 64-lane linear staging writes.
__device__ __forceinline__ int swz(int row, int chunk) {
  int slot = (((row & 1) << 2) | chunk) ^ ((row >> 1) & 7);
  return ((row >> 1) << 7) + (slot << 4);
}

// Stage NLOADS*512 16B-chunks (NLOADS*128 rows x 32 bf16) global -> LDS.
// LDS dest is linear (gload_lds HW requirement); the SOURCE address is
// pre-inverse-swizzled so that swz()-reads see a row-major tile (rule #21).
// Local rows > row_max are clamped (duplicate loads into never-read slots).
template <int NLOADS>
__device__ __forceinline__ void stage(const bf16_t* __restrict__ src,
                                      int row_base, int row_max, int k0,
                                      char* ldsb, int tid) {
#pragma unroll
  for (int i = 0; i < NLOADS; ++i) {
    const int c = i * 512 + tid;     // linear 16B-chunk index this thread covers
    const int rp = c >> 3;
    const int slot = c & 7;
    const int v = slot ^ (rp & 7);   // inverse swizzle
    int srow = rp * 2 + (v >> 2);
    if (srow > row_max) srow = row_max;
    const bf16_t* g = src + (size_t)(row_base + srow) * HID + k0 + (v & 3) * 8;
    GLD16(g, ldsb + (size_t)(i * 512 + (tid & ~63)) * 16);  // wave-uniform base
  }
}

// ---------------------------------------------------------------------------
// K1: fp32 -> bf16 conversion of hs, gate_up_w, down_w (contiguous in ws)
// ---------------------------------------------------------------------------
__global__ __launch_bounds__(256) void convert3(const float* __restrict__ a,
                                                const float* __restrict__ b,
                                                const float* __restrict__ c,
                                                bf16_t* __restrict__ o) {
  constexpr size_t na = (size_t)SEQ * HID;
  constexpr size_t nb = (size_t)(2 * INTER) * HID;
  constexpr size_t nc = (size_t)HID * INTER;
  size_t i = ((size_t)blockIdx.x * 256 + threadIdx.x) * 4;
  if (i >= na + nb + nc) return;
  const float* src;
  if (i < na)            src = a + i;
  else if (i < na + nb)  src = b + (i - na);
  else                   src = c + (i - na - nb);
  float4 v = *(const float4*)src;
  bf16x4 r = {(bf16_t)v.x, (bf16_t)v.y, (bf16_t)v.z, (bf16_t)v.w};
  *(bf16x4*)(o + i) = r;
}

// ---------------------------------------------------------------------------
// K2: fused gate/up GEMM + silu.  BM=256, BN=96 (per mat), 8 waves (4M x 2N),
// per-wave 64x48 per mat, 16x16x32 MFMA.  LDS slot = A 16K + G 8K + U 8K,
// ring-4 = 128 KiB.  Per K-tile (ONE phase, ONE barrier):
//   { read af[4],gf[3],uf[3]; stage A,G,U for t+3; 24 MFMA; vmcnt; barrier }
// ---------------------------------------------------------------------------
__global__ __launch_bounds__(512, 2) void gemm1(const bf16_t* __restrict__ A,
                                                const bf16_t* __restrict__ GW,
                                                const float* __restrict__ bias,
                                                bf16_t* __restrict__ X) {
  __shared__ char sm[4 * 32768];
  const bf16_t* UW = GW + (size_t)INTER * HID;  // up half of gate_up_w

  const int tid = threadIdx.x;
  const int w = tid >> 6, l = tid & 63;
  const int wm = w >> 1, wn = w & 1;  // 4M x 2N
  const int l15 = l & 15, l4 = l >> 4;
  const int row0 = blockIdx.x * 256;
  const int col0 = blockIdx.y * 96;

  // Loop-invariant LDS read offsets (A at 0, G at 16384, U at 24576).
  int rdA[4], rdG[3], rdU[3];
#pragma unroll
  for (int m = 0; m < 4; ++m) rdA[m] = swz(wm * 64 + m * 16 + l15, l4);
#pragma unroll
  for (int n = 0; n < 3; ++n) {
    rdG[n] = 16384 + swz(wn * 48 + n * 16 + l15, l4);
    rdU[n] = 24576 + swz(wn * 48 + n * 16 + l15, l4);
  }

  f32x4 accg[4][3], accu[4][3];
#pragma unroll
  for (int m = 0; m < 4; ++m)
#pragma unroll
    for (int n = 0; n < 3; ++n) {
      accg[m][n] = (f32x4){0.f, 0.f, 0.f, 0.f};
      accu[m][n] = (f32x4){0.f, 0.f, 0.f, 0.f};
    }

  // Prologue: stage K-tiles 0,1,2 (4 loads/thread each); retire t0's, keep 8.
  for (int t = 0; t < 3; ++t) {
    char* s = sm + t * 32768;
    stage<2>(A, row0, 255, t * BK, s, tid);
    stage<1>(GW, col0, 95, t * BK, s + 16384, tid);
    stage<1>(UW, col0, 95, t * BK, s + 24576, tid);
  }
  VMCNT(8);
  BARRIER();

#pragma unroll 1
  for (int t = 0; t < NT; ++t) {
    char* sa = sm + (t & 3) * 32768;
    char* ss = sm + ((t + 3) & 3) * 32768;

    bf16x8 af[4], gf[3], uf[3];
#pragma unroll
    for (int m = 0; m < 4; ++m) af[m] = *(const bf16x8*)(sa + rdA[m]);
#pragma unroll
    for (int n = 0; n < 3; ++n) {
      gf[n] = *(const bf16x8*)(sa + rdG[n]);
      uf[n] = *(const bf16x8*)(sa + rdU[n]);
    }
    if (t + 3 < NT) {
      stage<2>(A, row0, 255, (t + 3) * BK, ss, tid);
      stage<1>(GW, col0, 95, (t + 3) * BK, ss + 16384, tid);
      stage<1>(UW, col0, 95, (t + 3) * BK, ss + 24576, tid);
    }
    __builtin_amdgcn_s_setprio(1);
#pragma unroll
    for (int m = 0; m < 4; ++m)
#pragma unroll
      for (int n = 0; n < 3; ++n) {
        accg[m][n] = __builtin_amdgcn_mfma_f32_16x16x32_bf16(af[m], gf[n], accg[m][n], 0, 0, 0);
        accu[m][n] = __builtin_amdgcn_mfma_f32_16x16x32_bf16(af[m], uf[n], accu[m][n], 0, 0, 0);
      }
    __builtin_amdgcn_s_setprio(0);
    // Boundary: retire K-tile t+1's 4 loads, keep (t+2),(t+3) = 8 in flight.
    if (t < NT - 3)       { VMCNT(8); }
    else if (t == NT - 3) { VMCNT(4); }
    else if (t == NT - 2) { VMCNT(0); }
    BARRIER();
  }

  // Epilogue: x = (gate+bg) * silu(up+bu).  C/D: col=lane&15, row=(lane>>4)*4+j.
#pragma unroll
  for (int n = 0; n < 3; ++n) {
    const int col = col0 + wn * 48 + n * 16 + l15;
    const float bg = bias[col];
    const float bu = bias[INTER + col];
#pragma unroll
    for (int m = 0; m < 4; ++m) {
      const int r = row0 + wm * 64 + m * 16 + l4 * 4;
#pragma unroll
      for (int j = 0; j < 4; ++j) {
        const float g = accg[m][n][j] + bg;
        const float u = accu[m][n][j] + bu;
        X[(size_t)(r + j) * INTER + col] = (bf16_t)(g * (u / (1.f + __expf(-u))));
      }
    }
  }
}

// ---------------------------------------------------------------------------
// K3: out = x @ down_w^T + down_b.  BM=256, BN=192, 8 waves (4M x 2N),
// per-wave 64x96.  LDS slot = A 16K + B 16K (B staged 256 rows, 192 used),
// ring-4 = 128 KiB.  Same one-phase/one-barrier K-tile as gemm1.
// ---------------------------------------------------------------------------
__global__ __launch_bounds__(512, 2) void gemm2(const bf16_t* __restrict__ A,
                                                const bf16_t* __restrict__ B,
                                                const float* __restrict__ bias,
                                                float* __restrict__ out) {
  __shared__ char sm[4 * 32768];
  const int tid = threadIdx.x;
  const int w = tid >> 6, l = tid & 63;
  const int wm = w >> 1, wn = w & 1;
  const int l15 = l & 15, l4 = l >> 4;
  const int row0 = blockIdx.x * 256;
  const int col0 = blockIdx.y * 192;

  int rdA[4], rdB[6];
#pragma unroll
  for (int m = 0; m < 4; ++m) rdA[m] = swz(wm * 64 + m * 16 + l15, l4);
#pragma unroll
  for (int n = 0; n < 6; ++n) rdB[n] = 16384 + swz(wn * 96 + n * 16 + l15, l4);

  f32x4 acc[4][6];
#pragma unroll
  for (int m = 0; m < 4; ++m)
#pragma unroll
    for (int n = 0; n < 6; ++n) acc[m][n] = (f32x4){0.f, 0.f, 0.f, 0.f};

  for (int t = 0; t < 3; ++t) {
    char* s = sm + t * 32768;
    stage<2>(A, row0, 255, t * BK, s, tid);
    stage<2>(B, col0, 191, t * BK, s + 16384, tid);
  }
  VMCNT(8);
  BARRIER();

#pragma unroll 1
  for (int t = 0; t < NT; ++t) {
    char* sa = sm + (t & 3) * 32768;
    char* ss = sm + ((t + 3) & 3) * 32768;

    bf16x8 af[4], bfr[6];
#pragma unroll
    for (int m = 0; m < 4; ++m) af[m] = *(const bf16x8*)(sa + rdA[m]);
#pragma unroll
    for (int n = 0; n < 6; ++n) bfr[n] = *(const bf16x8*)(sa + rdB[n]);
    if (t + 3 < NT) {
      stage<2>(A, row0, 255, (t + 3) * BK, ss, tid);
      stage<2>(B, col0, 191, (t + 3) * BK, ss + 16384, tid);
    }
    __builtin_amdgcn_s_setprio(1);
#pragma unroll
    for (int m = 0; m < 4; ++m)
#pragma unroll
      for (int n = 0; n < 6; ++n)
        acc[m][n] = __builtin_amdgcn_mfma_f32_16x16x32_bf16(af[m], bfr[n], acc[m][n], 0, 0, 0);
    __builtin_amdgcn_s_setprio(0);
    if (t < NT - 3)       { VMCNT(8); }
    else if (t == NT - 3) { VMCNT(4); }
    else if (t == NT - 2) { VMCNT(0); }
    BARRIER();
  }

#pragma unroll
  for (int n = 0; n < 6; ++n) {
    const int col = col0 + wn * 96 + n * 16 + l15;
    const float bb = bias[col];
#pragma unroll
    for (int m = 0; m < 4; ++m) {
      const int r = row0 + wm * 64 + m * 16 + l4 * 4;
#pragma unroll
      for (int j = 0; j < 4; ++j)
        out[(size_t)(r + j) * HID + col] = acc[m][n][j] + bb;
    }
  }
}

// ---------------------------------------------------------------------------
extern "C" void kernel_launch(void* const* d_in, const int* in_sizes, int n_in,
                              void* d_out, int out_size, void* d_ws, size_t ws_size,
                              hipStream_t stream) {
  (void)in_sizes; (void)n_in; (void)out_size; (void)ws_size;

  const float* hs  = (const float*)d_in[0];  // (4096, 2880)
  // d_in[1] router_w, d_in[2] router_b: unused — sum(softmax(topk)) == 1.
  const float* guw = (const float*)d_in[3];  // (5760, 2880)
  const float* gub = (const float*)d_in[4];  // (5760,)
  const float* dww = (const float*)d_in[5];  // (2880, 2880)
  const float* dwb = (const float*)d_in[6];  // (2880,)
  float* out = (float*)d_out;                // (4096, 2880)

  constexpr size_t n_hs  = (size_t)SEQ * HID;
  constexpr size_t n_guw = (size_t)(2 * INTER) * HID;
  constexpr size_t n_dww = (size_t)HID * INTER;

  bf16_t* ws   = (bf16_t*)d_ws;
  bf16_t* hsb  = ws;
  bf16_t* guwb = hsb + n_hs;
  bf16_t* dwwb = guwb + n_guw;
  bf16_t* xb   = dwwb + n_dww;  // (4096, 2880) bf16

  const size_t total4 = (n_hs + n_guw + n_dww) / 4;
  const int cgrid = (int)((total4 + 255) / 256);
  convert3<<<cgrid, 256, 0, stream>>>(hs, guw, dww, ws);

  dim3 g1(SEQ / 256, INTER / 96);   // 16 x 30 = 480 blocks
  gemm1<<<g1, 512, 0, stream>>>(hsb, guwb, gub, xb);

  dim3 g2(SEQ / 256, HID / 192);    // 16 x 15 = 240 blocks
  gemm2<<<g2, 512, 0, stream>>>(xb, dwwb, dwb, out);
}

// Round 6
// 351.136 us; speedup vs baseline: 1.4339x; 1.0465x over previous
//
#include <hip/hip_runtime.h>
#include <hip/hip_bf16.h>

// GptOssMoEExperts on MI355X — round 6.
// Router is a no-op (sum of softmax over top-k == 1):
//   out = (gate * silu(up)) @ down_w^T + down_b,  [gate|up] = hs @ gate_up_w^T + b.
//
// Round-5 analysis: gemm1 was LDS-read-pipe co-bound (MFMA 931 cyc vs LDS-read
// 960 cyc per CU per K-tile -> MfmaUtil capped ~48%). Fix: bigger per-wave
// tile. gemm1 now BM=256 x BN=192(per mat), 8 waves as 2M x 4N, wave tile
// 128x(48+48): 14 ds_read_b128 per 48 MFMA -> LDS 1344 vs MFMA 1862 cyc.
// Grid 16x15 = 240 blocks (single round). Ring-3 LDS (40KB slot), prefetch 2
// ahead, counted vmcnt(5). gemm2 + convert3 unchanged from round 5.

typedef __bf16 bf16_t;
typedef bf16_t bf16x8 __attribute__((ext_vector_type(8)));
typedef bf16_t bf16x4 __attribute__((ext_vector_type(4)));
typedef float f32x4 __attribute__((ext_vector_type(4)));

#define SEQ   4096
#define HID   2880
#define INTER 2880
#define BK    32
#define NT    90   // 2880 / 32, same K depth for both GEMMs

#define GLD16(srcp, ldsp)                                                     \
  __builtin_amdgcn_global_load_lds(                                           \
      (const __attribute__((address_space(1))) unsigned int*)(srcp),          \
      (__attribute__((address_space(3))) unsigned int*)(ldsp), 16, 0, 0)

#define BARRIER()                                                             \
  do {                                                                        \
    __builtin_amdgcn_sched_barrier(0);                                        \
    __builtin_amdgcn_s_barrier();                                             \
    __builtin_amdgcn_sched_barrier(0);                                        \
  } while (0)

#define VMCNT(n) asm volatile("s_waitcnt vmcnt(" #n ")" ::: "memory")

// Byte offset inside a [rows][32 bf16] LDS tile, row-pair XOR swizzle.
// slot = ((row&1)<<2 | chunk) ^ ((row>>1)&7); byte = (row>>1)*128 + slot*16.
// Measured 0 bank conflicts (rounds 2/5). Note swz(row+16,c) = swz(row,c)+1024
// -> per-m/n read offsets fold into ds_read offset immediates.
__device__ __forceinline__ int swz(int row, int chunk) {
  int slot = (((row & 1) << 2) | chunk) ^ ((row >> 1) & 7);
  return ((row >> 1) << 7) + (slot << 4);
}

// Round-5 stage helper (used by gemm2): NLOADS*512 16B-chunks, linear LDS
// dest, inverse-swizzled global source (rule #21).
template <int NLOADS>
__device__ __forceinline__ void stage(const bf16_t* __restrict__ src,
                                      int row_base, int row_max, int k0,
                                      char* ldsb, int tid) {
#pragma unroll
  for (int i = 0; i < NLOADS; ++i) {
    const int c = i * 512 + tid;
    const int rp = c >> 3;
    const int slot = c & 7;
    const int v = slot ^ (rp & 7);
    int srow = rp * 2 + (v >> 2);
    if (srow > row_max) srow = row_max;
    const bf16_t* g = src + (size_t)(row_base + srow) * HID + k0 + (v & 3) * 8;
    GLD16(g, ldsb + (size_t)(i * 512 + (tid & ~63)) * 16);
  }
}

// ---------------------------------------------------------------------------
// K1: fp32 -> bf16 conversion of hs, gate_up_w, down_w (contiguous in ws)
// ---------------------------------------------------------------------------
__global__ __launch_bounds__(256) void convert3(const float* __restrict__ a,
                                                const float* __restrict__ b,
                                                const float* __restrict__ c,
                                                bf16_t* __restrict__ o) {
  constexpr size_t na = (size_t)SEQ * HID;
  constexpr size_t nb = (size_t)(2 * INTER) * HID;
  constexpr size_t nc = (size_t)HID * INTER;
  size_t i = ((size_t)blockIdx.x * 256 + threadIdx.x) * 4;
  if (i >= na + nb + nc) return;
  const float* src;
  if (i < na)            src = a + i;
  else if (i < na + nb)  src = b + (i - na);
  else                   src = c + (i - na - nb);
  float4 v = *(const float4*)src;
  bf16x4 r = {(bf16_t)v.x, (bf16_t)v.y, (bf16_t)v.z, (bf16_t)v.w};
  *(bf16x4*)(o + i) = r;
}

// ---------------------------------------------------------------------------
// K2: fused gate/up GEMM + silu.  BM=256, BN=192 per mat, 8 waves (2M x 4N),
// wave tile 128 x (48 gate + 48 up).  LDS slot = A 16K + G 12K + U 12K = 40K,
// ring-3 = 120 KiB.  Per thread per K-tile: 5 gload_lds (A 2, G/U 3).
// Per K-tile per wave: 6 + 8 ds_read_b128, 48 MFMA.  Counted vmcnt(5).
// ---------------------------------------------------------------------------
__global__ __launch_bounds__(512, 2) void gemm1(const bf16_t* __restrict__ A,
                                                const bf16_t* __restrict__ GW,
                                                const float* __restrict__ bias,
                                                bf16_t* __restrict__ X) {
  __shared__ char sm[3 * 40960];
  const bf16_t* UW = GW + (size_t)INTER * HID;  // up half of gate_up_w

  const int tid = threadIdx.x;
  const int w = tid >> 6, l = tid & 63;
  const int wm = w >> 2, wn = w & 3;            // 2M x 4N wave grid
  const int l15 = l & 15, l4 = l >> 4;
  const int row0 = blockIdx.x * 256;
  const int col0 = blockIdx.y * 192;

  // --- staging streams: 5 per thread (A c=tid,512+tid; GU c=i*512+tid) ---
  const bf16_t* pS[5];
  int dL[5];
#pragma unroll
  for (int i = 0; i < 2; ++i) {                 // A: 1024 chunks, rows 0..255
    const int c = i * 512 + tid;
    const int rp = c >> 3, sl = c & 7, v = sl ^ (rp & 7);
    const int srow = rp * 2 + (v >> 2);
    pS[i] = A + (size_t)(row0 + srow) * HID + (v & 3) * 8;
    dL[i] = (i * 512 + (tid & ~63)) * 16;
  }
#pragma unroll
  for (int i = 0; i < 3; ++i) {                 // G(768 chunks) then U(768)
    const int c = i * 512 + tid;
    const int cc = c < 768 ? c : c - 768;
    const bf16_t* const base = c < 768 ? GW : UW;
    const int rp = cc >> 3, sl = cc & 7, v = sl ^ (rp & 7);
    const int srow = rp * 2 + (v >> 2);         // 0..191, no clamp needed
    pS[2 + i] = base + (size_t)(col0 + srow) * HID + (v & 3) * 8;
    dL[2 + i] = 16384 + (i * 512 + (tid & ~63)) * 16;
  }

#define G1_STAGE(T, sb)                                                       \
  do {                                                                        \
    const int kk_ = (T) * BK;                                                 \
    _Pragma("unroll") for (int i_ = 0; i_ < 5; ++i_)                          \
      GLD16(pS[i_] + kk_, (sb) + dL[i_]);                                     \
  } while (0)

  // --- LDS read bases (A at 0, G at 16384, U at 28672); +1024 per 16 rows ---
  const int rdA = swz(wm * 128 + l15, l4);
  const int rdG = 16384 + swz(wn * 48 + l15, l4);
  const int rdU = rdG + 12288;

  f32x4 accg[8][3], accu[8][3];
#pragma unroll
  for (int m = 0; m < 8; ++m)
#pragma unroll
    for (int n = 0; n < 3; ++n) {
      accg[m][n] = (f32x4){0.f, 0.f, 0.f, 0.f};
      accu[m][n] = (f32x4){0.f, 0.f, 0.f, 0.f};
    }

  char* s0 = sm;
  char* s1 = sm + 40960;
  char* s2 = sm + 81920;

  // Prologue: stage tiles 0,1; wait tile 0 landed (5 of 10 retired).
  G1_STAGE(0, s0);
  G1_STAGE(1, s1);
  VMCNT(5);
  BARRIER();

#pragma unroll 1
  for (int t = 0; t < NT; ++t) {
    bf16x8 gf[3], uf[3];
#pragma unroll
    for (int n = 0; n < 3; ++n) {
      gf[n] = *(const bf16x8*)(s0 + rdG + n * 1024);
      uf[n] = *(const bf16x8*)(s0 + rdU + n * 1024);
    }
    if (t + 2 < NT) G1_STAGE(t + 2, s2);
    __builtin_amdgcn_s_setprio(1);
#pragma unroll
    for (int m = 0; m < 8; ++m) {
      const bf16x8 af = *(const bf16x8*)(s0 + rdA + m * 1024);
#pragma unroll
      for (int n = 0; n < 3; ++n) {
        accg[m][n] = __builtin_amdgcn_mfma_f32_16x16x32_bf16(af, gf[n], accg[m][n], 0, 0, 0);
        accu[m][n] = __builtin_amdgcn_mfma_f32_16x16x32_bf16(af, uf[n], accu[m][n], 0, 0, 0);
      }
    }
    __builtin_amdgcn_s_setprio(0);
    // Boundary: tile t+1 must be resident; keep t+2's 5 loads in flight.
    if (t < NT - 2)       { VMCNT(5); }
    else if (t == NT - 2) { VMCNT(0); }
    BARRIER();
    char* const sx = s0; s0 = s1; s1 = s2; s2 = sx;  // ring-3 rotate
  }

  // Epilogue: x = (gate+bg) * silu(up+bu).  C/D: col=lane&15, row=(lane>>4)*4+j.
#pragma unroll
  for (int n = 0; n < 3; ++n) {
    const int col = col0 + wn * 48 + n * 16 + l15;
    const float bg = bias[col];
    const float bu = bias[INTER + col];
#pragma unroll
    for (int m = 0; m < 8; ++m) {
      const int r = row0 + wm * 128 + m * 16 + l4 * 4;
#pragma unroll
      for (int j = 0; j < 4; ++j) {
        const float g = accg[m][n][j] + bg;
        const float u = accu[m][n][j] + bu;
        X[(size_t)(r + j) * INTER + col] = (bf16_t)(g * (u / (1.f + __expf(-u))));
      }
    }
  }
#undef G1_STAGE
}

// ---------------------------------------------------------------------------
// K3: out = x @ down_w^T + down_b.  UNCHANGED from round 5 (isolates gemm1's
// delta).  BM=256, BN=192, 8 waves (4M x 2N), wave 64x96, ring-4, vmcnt(8).
// ---------------------------------------------------------------------------
__global__ __launch_bounds__(512, 2) void gemm2(const bf16_t* __restrict__ A,
                                                const bf16_t* __restrict__ B,
                                                const float* __restrict__ bias,
                                                float* __restrict__ out) {
  __shared__ char sm[4 * 32768];
  const int tid = threadIdx.x;
  const int w = tid >> 6, l = tid & 63;
  const int wm = w >> 1, wn = w & 1;
  const int l15 = l & 15, l4 = l >> 4;
  const int row0 = blockIdx.x * 256;
  const int col0 = blockIdx.y * 192;

  int rdA[4], rdB[6];
#pragma unroll
  for (int m = 0; m < 4; ++m) rdA[m] = swz(wm * 64 + m * 16 + l15, l4);
#pragma unroll
  for (int n = 0; n < 6; ++n) rdB[n] = 16384 + swz(wn * 96 + n * 16 + l15, l4);

  f32x4 acc[4][6];
#pragma unroll
  for (int m = 0; m < 4; ++m)
#pragma unroll
    for (int n = 0; n < 6; ++n) acc[m][n] = (f32x4){0.f, 0.f, 0.f, 0.f};

  for (int t = 0; t < 3; ++t) {
    char* s = sm + t * 32768;
    stage<2>(A, row0, 255, t * BK, s, tid);
    stage<2>(B, col0, 191, t * BK, s + 16384, tid);
  }
  VMCNT(8);
  BARRIER();

#pragma unroll 1
  for (int t = 0; t < NT; ++t) {
    char* sa = sm + (t & 3) * 32768;
    char* ss = sm + ((t + 3) & 3) * 32768;

    bf16x8 af[4], bfr[6];
#pragma unroll
    for (int m = 0; m < 4; ++m) af[m] = *(const bf16x8*)(sa + rdA[m]);
#pragma unroll
    for (int n = 0; n < 6; ++n) bfr[n] = *(const bf16x8*)(sa + rdB[n]);
    if (t + 3 < NT) {
      stage<2>(A, row0, 255, (t + 3) * BK, ss, tid);
      stage<2>(B, col0, 191, (t + 3) * BK, ss + 16384, tid);
    }
    __builtin_amdgcn_s_setprio(1);
#pragma unroll
    for (int m = 0; m < 4; ++m)
#pragma unroll
      for (int n = 0; n < 6; ++n)
        acc[m][n] = __builtin_amdgcn_mfma_f32_16x16x32_bf16(af[m], bfr[n], acc[m][n], 0, 0, 0);
    __builtin_amdgcn_s_setprio(0);
    if (t < NT - 3)       { VMCNT(8); }
    else if (t == NT - 3) { VMCNT(4); }
    else if (t == NT - 2) { VMCNT(0); }
    BARRIER();
  }

#pragma unroll
  for (int n = 0; n < 6; ++n) {
    const int col = col0 + wn * 96 + n * 16 + l15;
    const float bb = bias[col];
#pragma unroll
    for (int m = 0; m < 4; ++m) {
      const int r = row0 + wm * 64 + m * 16 + l4 * 4;
#pragma unroll
      for (int j = 0; j < 4; ++j)
        out[(size_t)(r + j) * HID + col] = acc[m][n][j] + bb;
    }
  }
}

// ---------------------------------------------------------------------------
extern "C" void kernel_launch(void* const* d_in, const int* in_sizes, int n_in,
                              void* d_out, int out_size, void* d_ws, size_t ws_size,
                              hipStream_t stream) {
  (void)in_sizes; (void)n_in; (void)out_size; (void)ws_size;

  const float* hs  = (const float*)d_in[0];  // (4096, 2880)
  // d_in[1] router_w, d_in[2] router_b: unused — sum(softmax(topk)) == 1.
  const float* guw = (const float*)d_in[3];  // (5760, 2880)
  const float* gub = (const float*)d_in[4];  // (5760,)
  const float* dww = (const float*)d_in[5];  // (2880, 2880)
  const float* dwb = (const float*)d_in[6];  // (2880,)
  float* out = (float*)d_out;                // (4096, 2880)

  constexpr size_t n_hs  = (size_t)SEQ * HID;
  constexpr size_t n_guw = (size_t)(2 * INTER) * HID;
  constexpr size_t n_dww = (size_t)HID * INTER;

  bf16_t* ws   = (bf16_t*)d_ws;
  bf16_t* hsb  = ws;
  bf16_t* guwb = hsb + n_hs;
  bf16_t* dwwb = guwb + n_guw;
  bf16_t* xb   = dwwb + n_dww;  // (4096, 2880) bf16

  const size_t total4 = (n_hs + n_guw + n_dww) / 4;
  const int cgrid = (int)((total4 + 255) / 256);
  convert3<<<cgrid, 256, 0, stream>>>(hs, guw, dww, ws);

  dim3 g1(SEQ / 256, INTER / 192);  // 16 x 15 = 240 blocks, single round
  gemm1<<<g1, 512, 0, stream>>>(hsb, guwb, gub, xb);

  dim3 g2(SEQ / 256, HID / 192);    // 16 x 15 = 240 blocks
  gemm2<<<g2, 512, 0, stream>>>(xb, dwwb, dwb, out);
}